// Round 2
// baseline (377.230 us; speedup 1.0000x reference)
//
#include <hip/hip_runtime.h>
#include <math.h>

#define N_NODES 3000
#define T_STEPS 12
#define F_INP 2
#define HEADS 8
#define HID 32
#define E_EDGES 32000
#define E_TOT (E_EDGES + N_NODES)   // 35000 with self-loops
#define NEG_SLOPE 0.2f
#define OUT_F 24                    // F_OUT * T_OUT

__device__ __forceinline__ float sigm(float x) {
    return 1.0f / (1.0f + __expf(-x));
}
__device__ __forceinline__ float tanh_f(float x) {
    // stable: exp overflow -> inf -> 1; underflow -> 0 -> -1
    return 1.0f - 2.0f / (__expf(2.0f * x) + 1.0f);
}

// ---------------------------------------------------------------------------
// K1: h = X @ gat_w.T  (per t,n: 256 outputs), fused a_s / a_d head reductions
// h_feat layout: [t][n][h*32+c] ; a_s/a_d layout: [t][n][h]
// ---------------------------------------------------------------------------
__global__ __launch_bounds__(256) void k_lin(const float* __restrict__ X,
                                             const float* __restrict__ gat_w,
                                             const float* __restrict__ att_src,
                                             const float* __restrict__ att_dst,
                                             float* __restrict__ h_feat,
                                             float* __restrict__ a_s,
                                             float* __restrict__ a_d) {
    int bx = blockIdx.x;                 // t * N + n
    int t = bx / N_NODES, n = bx % N_NODES;
    int tid = threadIdx.x;               // = h*32 + c
    float x0 = X[(n * T_STEPS + t) * F_INP + 0];
    float x1 = X[(n * T_STEPS + t) * F_INP + 1];
    float hv = x0 * gat_w[tid * 2 + 0] + x1 * gat_w[tid * 2 + 1];
    h_feat[((size_t)t * N_NODES + n) * 256 + tid] = hv;
    float ps = hv * att_src[tid];
    float pd = hv * att_dst[tid];
    for (int m = 16; m; m >>= 1) {
        ps += __shfl_xor(ps, m, 32);
        pd += __shfl_xor(pd, m, 32);
    }
    if ((tid & 31) == 0) {
        int h = tid >> 5;
        a_s[((size_t)t * N_NODES + n) * HEADS + h] = ps;
        a_d[((size_t)t * N_NODES + n) * HEADS + h] = pd;
    }
}

// ---------------------------------------------------------------------------
// CSR build: zero, degree histogram, single-block scan, scatter
// ---------------------------------------------------------------------------
__global__ void k_zero(int* __restrict__ p, int n) {
    int i = blockIdx.x * blockDim.x + threadIdx.x;
    if (i < n) p[i] = 0;
}

__global__ void k_deg(const int* __restrict__ ei, int* __restrict__ deg) {
    int i = blockIdx.x * blockDim.x + threadIdx.x;
    if (i >= E_TOT) return;
    int d = (i < E_EDGES) ? ei[E_EDGES + i] : (i - E_EDGES);
    atomicAdd(&deg[d], 1);
}

__global__ __launch_bounds__(256) void k_scan(const int* __restrict__ deg,
                                              int* __restrict__ row_start,
                                              int* __restrict__ cursor) {
    __shared__ int part[256];
    int tid = threadIdx.x;
    const int CH = (N_NODES + 255) / 256;   // 12
    int base = tid * CH;
    int s = 0;
    for (int i = 0; i < CH; i++) {
        int idx = base + i;
        if (idx < N_NODES) s += deg[idx];
    }
    part[tid] = s;
    __syncthreads();
    if (tid == 0) {
        int run = 0;
        for (int i = 0; i < 256; i++) { int tmp = part[i]; part[i] = run; run += tmp; }
        row_start[N_NODES] = run;           // == E_TOT
    }
    __syncthreads();
    int off = part[tid];
    for (int i = 0; i < CH; i++) {
        int idx = base + i;
        if (idx < N_NODES) {
            row_start[idx] = off;
            cursor[idx] = off;
            off += deg[idx];
        }
    }
}

__global__ void k_scatter(const int* __restrict__ ei, int* __restrict__ cursor,
                          int* __restrict__ csr_src) {
    int i = blockIdx.x * blockDim.x + threadIdx.x;
    if (i >= E_TOT) return;
    int s, d;
    if (i < E_EDGES) { s = ei[i]; d = ei[E_EDGES + i]; }
    else             { s = i - E_EDGES; d = s; }
    int pos = atomicAdd(&cursor[d], 1);
    csr_src[pos] = s;
}

// ---------------------------------------------------------------------------
// K5: segment softmax per destination node.
// block = 1 dst node, 8 head-groups x 32 lanes; loop over t.
// alpha layout: [t*8+h][pos]  (coalesced writes, broadcast-friendly reads)
// ---------------------------------------------------------------------------
__global__ __launch_bounds__(256) void k_softmax(const float* __restrict__ a_s,
                                                 const float* __restrict__ a_d,
                                                 const int* __restrict__ row_start,
                                                 const int* __restrict__ csr_src,
                                                 float* __restrict__ alpha) {
    int n = blockIdx.x;
    int tid = threadIdx.x;
    int h = tid >> 5, lane = tid & 31;
    int rs = row_start[n];
    int deg = row_start[n + 1] - rs;
    for (int t = 0; t < T_STEPS; t++) {
        float ad = a_d[((size_t)t * N_NODES + n) * HEADS + h];
        // pass 1: max
        float m = -1e30f;
        for (int i = lane; i < deg; i += 32) {
            int src = csr_src[rs + i];
            float s = a_s[((size_t)t * N_NODES + src) * HEADS + h] + ad;
            s = (s > 0.0f) ? s : NEG_SLOPE * s;
            m = fmaxf(m, s);
        }
        for (int mm = 16; mm; mm >>= 1) m = fmaxf(m, __shfl_xor(m, mm, 32));
        // pass 2: denominator
        float den = 0.0f;
        for (int i = lane; i < deg; i += 32) {
            int src = csr_src[rs + i];
            float s = a_s[((size_t)t * N_NODES + src) * HEADS + h] + ad;
            s = (s > 0.0f) ? s : NEG_SLOPE * s;
            den += __expf(s - m);
        }
        for (int mm = 16; mm; mm >>= 1) den += __shfl_xor(den, mm, 32);
        float inv = 1.0f / den;
        // pass 3: alpha
        float* arow = alpha + (size_t)(t * HEADS + h) * E_TOT;
        for (int i = lane; i < deg; i += 32) {
            int src = csr_src[rs + i];
            float s = a_s[((size_t)t * N_NODES + src) * HEADS + h] + ad;
            s = (s > 0.0f) ? s : NEG_SLOPE * s;
            arow[rs + i] = __expf(s - m) * inv;
        }
    }
}

// ---------------------------------------------------------------------------
// K6: aggregation + head mean + bias.
// block = (t,n); 256 threads = (h,c); per edge: coalesced 1KB read of h[src].
// gat_out layout: [n][t][c]  (node-major for the LSTM)
// ---------------------------------------------------------------------------
__global__ __launch_bounds__(256) void k_agg(const float* __restrict__ h_feat,
                                             const float* __restrict__ alpha,
                                             const int* __restrict__ row_start,
                                             const int* __restrict__ csr_src,
                                             const float* __restrict__ gat_b,
                                             float* __restrict__ gat_out) {
    int bx = blockIdx.x;                 // t * N + n
    int t = bx / N_NODES, n = bx % N_NODES;
    int tid = threadIdx.x;
    int h = tid >> 5, c = tid & 31;
    int rs = row_start[n];
    int deg = row_start[n + 1] - rs;
    const float* hf_t = h_feat + (size_t)t * N_NODES * 256;
    const float* arow = alpha + (size_t)(t * HEADS + h) * E_TOT;
    float acc = 0.0f;
    for (int i = 0; i < deg; i++) {
        int pos = rs + i;
        int src = csr_src[pos];
        float al = arow[pos];
        acc += al * hf_t[(size_t)src * 256 + tid];
    }
    __shared__ float red[256];
    red[tid] = acc;
    __syncthreads();
    if (h == 0) {
        float s = 0.0f;
        #pragma unroll
        for (int hh = 0; hh < HEADS; hh++) s += red[hh * 32 + c];
        gat_out[((size_t)n * T_STEPS + t) * HID + c] = s * 0.125f + gat_b[c];
    }
}

// ---------------------------------------------------------------------------
// LSTM layer 0: 32 lanes per node, gates via width-32 shuffles + LDS float4
// transposed weights T[k][j] = (w[i], w[f], w[g], w[o]) column k, row j.
// ---------------------------------------------------------------------------
__global__ __launch_bounds__(256) void k_lstm0(const float* __restrict__ xs,   // [n][t][32]
                                               const float* __restrict__ w_ih,
                                               const float* __restrict__ w_hh,
                                               const float* __restrict__ b_ih,
                                               const float* __restrict__ b_hh,
                                               float* __restrict__ hs_out) {   // [n][t][32]
    __shared__ float4 Tih[1024];   // [k*32 + j]
    __shared__ float4 Thh[1024];
    __shared__ float4 bb[32];
    int tid = threadIdx.x;
    for (int idx = tid; idx < 1024; idx += 256) {
        int k = idx >> 5, jj = idx & 31;
        Tih[idx] = make_float4(w_ih[jj * 32 + k], w_ih[(32 + jj) * 32 + k],
                               w_ih[(64 + jj) * 32 + k], w_ih[(96 + jj) * 32 + k]);
        Thh[idx] = make_float4(w_hh[jj * 32 + k], w_hh[(32 + jj) * 32 + k],
                               w_hh[(64 + jj) * 32 + k], w_hh[(96 + jj) * 32 + k]);
    }
    if (tid < 32) {
        bb[tid] = make_float4(b_ih[tid] + b_hh[tid],
                              b_ih[32 + tid] + b_hh[32 + tid],
                              b_ih[64 + tid] + b_hh[64 + tid],
                              b_ih[96 + tid] + b_hh[96 + tid]);
    }
    __syncthreads();
    int node = blockIdx.x * 8 + (tid >> 5);
    int j = tid & 31;
    float h = 0.0f, c = 0.0f;
    for (int t = 0; t < T_STEPS; t++) {
        float x = xs[((size_t)node * T_STEPS + t) * HID + j];
        float4 b = bb[j];
        float gi = b.x, gf = b.y, gg = b.z, go = b.w;
        #pragma unroll
        for (int k = 0; k < 32; k++) {
            float xk = __shfl(x, k, 32);
            float hk = __shfl(h, k, 32);
            float4 wi = Tih[k * 32 + j];
            float4 wh = Thh[k * 32 + j];
            gi = fmaf(xk, wi.x, fmaf(hk, wh.x, gi));
            gf = fmaf(xk, wi.y, fmaf(hk, wh.y, gf));
            gg = fmaf(xk, wi.z, fmaf(hk, wh.z, gg));
            go = fmaf(xk, wi.w, fmaf(hk, wh.w, go));
        }
        c = sigm(gf) * c + sigm(gi) * tanh_f(gg);
        h = sigm(go) * tanh_f(c);
        hs_out[((size_t)node * T_STEPS + t) * HID + j] = h;
    }
}

// ---------------------------------------------------------------------------
// LSTM layer 1 + FC head (only h at t=T-1 is needed downstream).
// ---------------------------------------------------------------------------
__global__ __launch_bounds__(256) void k_lstm1(const float* __restrict__ xs,   // [n][t][32]
                                               const float* __restrict__ w_ih,
                                               const float* __restrict__ w_hh,
                                               const float* __restrict__ b_ih,
                                               const float* __restrict__ b_hh,
                                               const float* __restrict__ fc_w,
                                               const float* __restrict__ fc_b,
                                               float* __restrict__ out) {      // [n][24]
    __shared__ float4 Tih[1024];
    __shared__ float4 Thh[1024];
    __shared__ float4 bb[32];
    __shared__ float fcT[32 * 32];   // [k][j], zero-padded j>=24
    int tid = threadIdx.x;
    for (int idx = tid; idx < 1024; idx += 256) {
        int k = idx >> 5, jj = idx & 31;
        Tih[idx] = make_float4(w_ih[jj * 32 + k], w_ih[(32 + jj) * 32 + k],
                               w_ih[(64 + jj) * 32 + k], w_ih[(96 + jj) * 32 + k]);
        Thh[idx] = make_float4(w_hh[jj * 32 + k], w_hh[(32 + jj) * 32 + k],
                               w_hh[(64 + jj) * 32 + k], w_hh[(96 + jj) * 32 + k]);
        fcT[k * 32 + jj] = (jj < OUT_F) ? fc_w[jj * 32 + k] : 0.0f;
    }
    if (tid < 32) {
        bb[tid] = make_float4(b_ih[tid] + b_hh[tid],
                              b_ih[32 + tid] + b_hh[32 + tid],
                              b_ih[64 + tid] + b_hh[64 + tid],
                              b_ih[96 + tid] + b_hh[96 + tid]);
    }
    __syncthreads();
    int node = blockIdx.x * 8 + (tid >> 5);
    int j = tid & 31;
    float h = 0.0f, c = 0.0f;
    for (int t = 0; t < T_STEPS; t++) {
        float x = xs[((size_t)node * T_STEPS + t) * HID + j];
        float4 b = bb[j];
        float gi = b.x, gf = b.y, gg = b.z, go = b.w;
        #pragma unroll
        for (int k = 0; k < 32; k++) {
            float xk = __shfl(x, k, 32);
            float hk = __shfl(h, k, 32);
            float4 wi = Tih[k * 32 + j];
            float4 wh = Thh[k * 32 + j];
            gi = fmaf(xk, wi.x, fmaf(hk, wh.x, gi));
            gf = fmaf(xk, wi.y, fmaf(hk, wh.y, gf));
            gg = fmaf(xk, wi.z, fmaf(hk, wh.z, gg));
            go = fmaf(xk, wi.w, fmaf(hk, wh.w, go));
        }
        c = sigm(gf) * c + sigm(gi) * tanh_f(gg);
        h = sigm(go) * tanh_f(c);
    }
    float acc = (j < OUT_F) ? fc_b[j] : 0.0f;
    #pragma unroll
    for (int k = 0; k < 32; k++) {
        float hk = __shfl(h, k, 32);
        acc = fmaf(hk, fcT[k * 32 + j], acc);
    }
    if (j < OUT_F) out[(size_t)node * OUT_F + j] = acc;
}

// ---------------------------------------------------------------------------
extern "C" void kernel_launch(void* const* d_in, const int* in_sizes, int n_in,
                              void* d_out, int out_size, void* d_ws, size_t ws_size,
                              hipStream_t stream) {
    (void)in_sizes; (void)n_in; (void)out_size; (void)ws_size;
    const float* X       = (const float*)d_in[0];
    const int*   ei      = (const int*)d_in[1];
    const float* gat_w   = (const float*)d_in[2];
    const float* att_src = (const float*)d_in[3];
    const float* att_dst = (const float*)d_in[4];
    const float* gat_b   = (const float*)d_in[5];
    const float* w_ih0   = (const float*)d_in[6];
    const float* w_hh0   = (const float*)d_in[7];
    const float* b_ih0   = (const float*)d_in[8];
    const float* b_hh0   = (const float*)d_in[9];
    const float* w_ih1   = (const float*)d_in[10];
    const float* w_hh1   = (const float*)d_in[11];
    const float* b_ih1   = (const float*)d_in[12];
    const float* b_hh1   = (const float*)d_in[13];
    const float* fc_w    = (const float*)d_in[14];
    const float* fc_b    = (const float*)d_in[15];
    float* out = (float*)d_out;

    char* ws = (char*)d_ws;
    size_t off = 0;
    auto alloc_f = [&](size_t n) { float* p = (float*)(ws + off); off += n * sizeof(float); return p; };
    auto alloc_i = [&](size_t n) { int* p = (int*)(ws + off); off += n * sizeof(int); return p; };

    float* h_feat  = alloc_f((size_t)T_STEPS * N_NODES * 256);   // 9.22M
    float* a_s     = alloc_f((size_t)T_STEPS * N_NODES * HEADS); // 288K
    float* a_d     = alloc_f((size_t)T_STEPS * N_NODES * HEADS); // 288K
    float* alpha   = alloc_f((size_t)T_STEPS * HEADS * E_TOT);   // 3.36M
    float* gat_out = alloc_f((size_t)N_NODES * T_STEPS * HID);   // 1.15M
    float* hs0     = alloc_f((size_t)N_NODES * T_STEPS * HID);   // 1.15M
    int* deg       = alloc_i(N_NODES);
    int* row_start = alloc_i(N_NODES + 1);
    int* cursor    = alloc_i(N_NODES);
    int* csr_src   = alloc_i(E_TOT);

    // GAT linear + attention coefficients
    k_lin<<<T_STEPS * N_NODES, 256, 0, stream>>>(X, gat_w, att_src, att_dst,
                                                 h_feat, a_s, a_d);
    // CSR by destination
    k_zero<<<(N_NODES + 255) / 256, 256, 0, stream>>>(deg, N_NODES);
    k_deg<<<(E_TOT + 255) / 256, 256, 0, stream>>>(ei, deg);
    k_scan<<<1, 256, 0, stream>>>(deg, row_start, cursor);
    k_scatter<<<(E_TOT + 255) / 256, 256, 0, stream>>>(ei, cursor, csr_src);
    // segment softmax
    k_softmax<<<N_NODES, 256, 0, stream>>>(a_s, a_d, row_start, csr_src, alpha);
    // aggregation + head mean + bias
    k_agg<<<T_STEPS * N_NODES, 256, 0, stream>>>(h_feat, alpha, row_start, csr_src,
                                                 gat_b, gat_out);
    // 2-layer LSTM + FC
    k_lstm0<<<N_NODES / 8, 256, 0, stream>>>(gat_out, w_ih0, w_hh0, b_ih0, b_hh0, hs0);
    k_lstm1<<<N_NODES / 8, 256, 0, stream>>>(hs0, w_ih1, w_hh1, b_ih1, b_hh1,
                                             fc_w, fc_b, out);
}

// Round 3
// 211.322 us; speedup vs baseline: 1.7851x; 1.7851x over previous
//
#include <hip/hip_runtime.h>
#include <math.h>

#define N_NODES 3000
#define T_STEPS 12
#define F_INP 2
#define HEADS 8
#define HID 32
#define E_EDGES 32000
#define E_TOT (E_EDGES + N_NODES)   // 35000 with self-loops
#define NEG_SLOPE 0.2f
#define OUT_F 24                    // F_OUT * T_OUT
#define MAXDEG 256                  // LDS staging capacity (actual max indeg ~30)

__device__ __forceinline__ float sigm(float x) {
    return 1.0f / (1.0f + __expf(-x));
}
__device__ __forceinline__ float tanh_f(float x) {
    return 1.0f - 2.0f / (__expf(2.0f * x) + 1.0f);
}

// ---------------------------------------------------------------------------
// k_prep: proj[w*8+h], w=0: <gw_f0, att_src>, 1: <gw_f1, att_src>,
//                      2: <gw_f0, att_dst>, 3: <gw_f1, att_dst>
// gat_w is (256,2) row-major; att_* is (8,32).
// ---------------------------------------------------------------------------
__global__ void k_prep(const float* __restrict__ gat_w,
                       const float* __restrict__ att_src,
                       const float* __restrict__ att_dst,
                       float* __restrict__ proj) {
    int tid = threadIdx.x;           // 0..31
    if (tid >= 32) return;
    int h = tid & 7, w = tid >> 3;   // w: 0..3
    const float* att = (w < 2) ? att_src : att_dst;
    int f = w & 1;
    float s = 0.0f;
    for (int c = 0; c < 32; c++)
        s += gat_w[((h * 32 + c) * 2) + f] * att[h * 32 + c];
    proj[w * 8 + h] = s;
}

// ---------------------------------------------------------------------------
// CSR build: zero, degree histogram, single-block scan, scatter
// ---------------------------------------------------------------------------
__global__ void k_zero(int* __restrict__ p, int n) {
    int i = blockIdx.x * blockDim.x + threadIdx.x;
    if (i < n) p[i] = 0;
}

__global__ void k_deg(const int* __restrict__ ei, int* __restrict__ deg) {
    int i = blockIdx.x * blockDim.x + threadIdx.x;
    if (i >= E_TOT) return;
    int d = (i < E_EDGES) ? ei[E_EDGES + i] : (i - E_EDGES);
    atomicAdd(&deg[d], 1);
}

__global__ __launch_bounds__(256) void k_scan(const int* __restrict__ deg,
                                              int* __restrict__ row_start,
                                              int* __restrict__ cursor) {
    __shared__ int part[256];
    int tid = threadIdx.x;
    const int CH = (N_NODES + 255) / 256;   // 12
    int base = tid * CH;
    int s = 0;
    for (int i = 0; i < CH; i++) {
        int idx = base + i;
        if (idx < N_NODES) s += deg[idx];
    }
    part[tid] = s;
    __syncthreads();
    if (tid == 0) {
        int run = 0;
        for (int i = 0; i < 256; i++) { int tmp = part[i]; part[i] = run; run += tmp; }
        row_start[N_NODES] = run;           // == E_TOT
    }
    __syncthreads();
    int off = part[tid];
    for (int i = 0; i < CH; i++) {
        int idx = base + i;
        if (idx < N_NODES) {
            row_start[idx] = off;
            cursor[idx] = off;
            off += deg[idx];
        }
    }
}

__global__ void k_scatter(const int* __restrict__ ei, int* __restrict__ cursor,
                          int* __restrict__ csr_src) {
    int i = blockIdx.x * blockDim.x + threadIdx.x;
    if (i >= E_TOT) return;
    int s, d;
    if (i < E_EDGES) { s = ei[i]; d = ei[E_EDGES + i]; }
    else             { s = i - E_EDGES; d = s; }
    int pos = atomicAdd(&cursor[d], 1);
    csr_src[pos] = s;
}

// ---------------------------------------------------------------------------
// k_gat: fused lin + softmax + aggregation + head-mean + bias, using the
// rank-2 structure: agg = (sum alpha*x0)*gw0 + (sum alpha*x1)*gw1.
// block = (t,n); 256 threads = 8 head-groups x 32 lanes.
// Per edge we only need x0,x1 of the source (8 B), staged in LDS.
// gat_out layout: [n][t][c]  (node-major for the LSTM)
// ---------------------------------------------------------------------------
__global__ __launch_bounds__(256) void k_gat(const float* __restrict__ X,
                                             const int* __restrict__ row_start,
                                             const int* __restrict__ csr_src,
                                             const float* __restrict__ proj,
                                             const float* __restrict__ gat_w,
                                             const float* __restrict__ gat_b,
                                             float* __restrict__ gat_out) {
    int bx = blockIdx.x;                 // t * N + n
    int t = bx / N_NODES, n = bx % N_NODES;
    int tid = threadIdx.x;
    int h = tid >> 5, lane = tid & 31;
    __shared__ float sx0[MAXDEG], sx1[MAXDEG];
    __shared__ float sS0[HEADS], sS1[HEADS];
    int rs = row_start[n];
    int deg = row_start[n + 1] - rs;     // >= 1 (self-loop)
    // stage source features (8 B per edge)
    for (int i = tid; i < deg && i < MAXDEG; i += 256) {
        int src = csr_src[rs + i];
        sx0[i] = X[(src * T_STEPS + t) * F_INP + 0];
        sx1[i] = X[(src * T_STEPS + t) * F_INP + 1];
    }
    __syncthreads();
    float ps0 = proj[h], ps1 = proj[8 + h];
    float pd0 = proj[16 + h], pd1 = proj[24 + h];
    float xd0 = X[(n * T_STEPS + t) * F_INP + 0];
    float xd1 = X[(n * T_STEPS + t) * F_INP + 1];
    float ad = xd0 * pd0 + xd1 * pd1;

    // pass 1: max
    float m = -1e30f;
    for (int i = lane; i < deg; i += 32) {
        float x0i, x1i;
        if (i < MAXDEG) { x0i = sx0[i]; x1i = sx1[i]; }
        else { int s2 = csr_src[rs + i];
               x0i = X[(s2 * T_STEPS + t) * F_INP + 0];
               x1i = X[(s2 * T_STEPS + t) * F_INP + 1]; }
        float s = x0i * ps0 + x1i * ps1 + ad;
        s = (s > 0.0f) ? s : NEG_SLOPE * s;
        m = fmaxf(m, s);
    }
    for (int mm = 16; mm; mm >>= 1) m = fmaxf(m, __shfl_xor(m, mm, 32));
    // pass 2: denominator
    float den = 0.0f;
    for (int i = lane; i < deg; i += 32) {
        float x0i, x1i;
        if (i < MAXDEG) { x0i = sx0[i]; x1i = sx1[i]; }
        else { int s2 = csr_src[rs + i];
               x0i = X[(s2 * T_STEPS + t) * F_INP + 0];
               x1i = X[(s2 * T_STEPS + t) * F_INP + 1]; }
        float s = x0i * ps0 + x1i * ps1 + ad;
        s = (s > 0.0f) ? s : NEG_SLOPE * s;
        den += __expf(s - m);
    }
    for (int mm = 16; mm; mm >>= 1) den += __shfl_xor(den, mm, 32);
    float inv = 1.0f / den;
    // pass 3: weighted sums of source scalars
    float S0 = 0.0f, S1 = 0.0f;
    for (int i = lane; i < deg; i += 32) {
        float x0i, x1i;
        if (i < MAXDEG) { x0i = sx0[i]; x1i = sx1[i]; }
        else { int s2 = csr_src[rs + i];
               x0i = X[(s2 * T_STEPS + t) * F_INP + 0];
               x1i = X[(s2 * T_STEPS + t) * F_INP + 1]; }
        float s = x0i * ps0 + x1i * ps1 + ad;
        s = (s > 0.0f) ? s : NEG_SLOPE * s;
        float a = __expf(s - m);
        S0 = fmaf(a, x0i, S0);
        S1 = fmaf(a, x1i, S1);
    }
    for (int mm = 16; mm; mm >>= 1) {
        S0 += __shfl_xor(S0, mm, 32);
        S1 += __shfl_xor(S1, mm, 32);
    }
    if (lane == 0) { sS0[h] = S0 * inv; sS1[h] = S1 * inv; }
    __syncthreads();
    // projection: out[c] = bias + (1/8) sum_h (S0[h]*gw0[h,c] + S1[h]*gw1[h,c])
    if (tid < HID) {
        int c = tid;
        float acc = gat_b[c];
        #pragma unroll
        for (int hh = 0; hh < HEADS; hh++) {
            float g0 = gat_w[((hh * 32 + c) * 2) + 0];
            float g1 = gat_w[((hh * 32 + c) * 2) + 1];
            acc = fmaf(0.125f * sS0[hh], g0, fmaf(0.125f * sS1[hh], g1, acc));
        }
        gat_out[((size_t)n * T_STEPS + t) * HID + c] = acc;
    }
}

// ---------------------------------------------------------------------------
// LSTM layer 0: 64 lanes per node, split-k (halves of k-range per 32-lane
// group), gates via width-32 shuffles + LDS float4 transposed weights.
// ---------------------------------------------------------------------------
__global__ __launch_bounds__(256) void k_lstm0(const float* __restrict__ xs,   // [n][t][32]
                                               const float* __restrict__ w_ih,
                                               const float* __restrict__ w_hh,
                                               const float* __restrict__ b_ih,
                                               const float* __restrict__ b_hh,
                                               float* __restrict__ hs_out) {   // [n][t][32]
    __shared__ float4 Tih[1024];   // [k*32 + j]
    __shared__ float4 Thh[1024];
    __shared__ float4 bb[32];
    int tid = threadIdx.x;
    for (int idx = tid; idx < 1024; idx += 256) {
        int k = idx >> 5, jj = idx & 31;
        Tih[idx] = make_float4(w_ih[jj * 32 + k], w_ih[(32 + jj) * 32 + k],
                               w_ih[(64 + jj) * 32 + k], w_ih[(96 + jj) * 32 + k]);
        Thh[idx] = make_float4(w_hh[jj * 32 + k], w_hh[(32 + jj) * 32 + k],
                               w_hh[(64 + jj) * 32 + k], w_hh[(96 + jj) * 32 + k]);
    }
    if (tid < 32) {
        bb[tid] = make_float4(b_ih[tid] + b_hh[tid],
                              b_ih[32 + tid] + b_hh[32 + tid],
                              b_ih[64 + tid] + b_hh[64 + tid],
                              b_ih[96 + tid] + b_hh[96 + tid]);
    }
    __syncthreads();
    int node = blockIdx.x * 4 + (tid >> 6);
    int lane64 = tid & 63;
    int j = lane64 & 31, half = lane64 >> 5;
    float h = 0.0f, c = 0.0f;                  // replicated in both halves
    for (int t = 0; t < T_STEPS; t++) {
        float x = xs[((size_t)node * T_STEPS + t) * HID + j];
        float4 b = bb[j];
        float gi = half ? 0.0f : b.x;
        float gf = half ? 0.0f : b.y;
        float gg = half ? 0.0f : b.z;
        float go = half ? 0.0f : b.w;
        #pragma unroll
        for (int kk = 0; kk < 16; kk++) {
            int k = (half << 4) + kk;
            float xk = __shfl(x, k, 32);
            float hk = __shfl(h, k, 32);
            float4 wi = Tih[k * 32 + j];
            float4 wh = Thh[k * 32 + j];
            gi = fmaf(xk, wi.x, fmaf(hk, wh.x, gi));
            gf = fmaf(xk, wi.y, fmaf(hk, wh.y, gf));
            gg = fmaf(xk, wi.z, fmaf(hk, wh.z, gg));
            go = fmaf(xk, wi.w, fmaf(hk, wh.w, go));
        }
        gi += __shfl_xor(gi, 32, 64);
        gf += __shfl_xor(gf, 32, 64);
        gg += __shfl_xor(gg, 32, 64);
        go += __shfl_xor(go, 32, 64);
        c = sigm(gf) * c + sigm(gi) * tanh_f(gg);
        h = sigm(go) * tanh_f(c);
        if (half == 0) hs_out[((size_t)node * T_STEPS + t) * HID + j] = h;
    }
}

// ---------------------------------------------------------------------------
// LSTM layer 1 + FC head (only h at t=T-1 is needed downstream).
// ---------------------------------------------------------------------------
__global__ __launch_bounds__(256) void k_lstm1(const float* __restrict__ xs,   // [n][t][32]
                                               const float* __restrict__ w_ih,
                                               const float* __restrict__ w_hh,
                                               const float* __restrict__ b_ih,
                                               const float* __restrict__ b_hh,
                                               const float* __restrict__ fc_w,
                                               const float* __restrict__ fc_b,
                                               float* __restrict__ out) {      // [n][24]
    __shared__ float4 Tih[1024];
    __shared__ float4 Thh[1024];
    __shared__ float4 bb[32];
    __shared__ float fcT[32 * 32];   // [k][j], zero-padded j>=24
    int tid = threadIdx.x;
    for (int idx = tid; idx < 1024; idx += 256) {
        int k = idx >> 5, jj = idx & 31;
        Tih[idx] = make_float4(w_ih[jj * 32 + k], w_ih[(32 + jj) * 32 + k],
                               w_ih[(64 + jj) * 32 + k], w_ih[(96 + jj) * 32 + k]);
        Thh[idx] = make_float4(w_hh[jj * 32 + k], w_hh[(32 + jj) * 32 + k],
                               w_hh[(64 + jj) * 32 + k], w_hh[(96 + jj) * 32 + k]);
        fcT[k * 32 + jj] = (jj < OUT_F) ? fc_w[jj * 32 + k] : 0.0f;
    }
    if (tid < 32) {
        bb[tid] = make_float4(b_ih[tid] + b_hh[tid],
                              b_ih[32 + tid] + b_hh[32 + tid],
                              b_ih[64 + tid] + b_hh[64 + tid],
                              b_ih[96 + tid] + b_hh[96 + tid]);
    }
    __syncthreads();
    int node = blockIdx.x * 4 + (tid >> 6);
    int lane64 = tid & 63;
    int j = lane64 & 31, half = lane64 >> 5;
    float h = 0.0f, c = 0.0f;
    for (int t = 0; t < T_STEPS; t++) {
        float x = xs[((size_t)node * T_STEPS + t) * HID + j];
        float4 b = bb[j];
        float gi = half ? 0.0f : b.x;
        float gf = half ? 0.0f : b.y;
        float gg = half ? 0.0f : b.z;
        float go = half ? 0.0f : b.w;
        #pragma unroll
        for (int kk = 0; kk < 16; kk++) {
            int k = (half << 4) + kk;
            float xk = __shfl(x, k, 32);
            float hk = __shfl(h, k, 32);
            float4 wi = Tih[k * 32 + j];
            float4 wh = Thh[k * 32 + j];
            gi = fmaf(xk, wi.x, fmaf(hk, wh.x, gi));
            gf = fmaf(xk, wi.y, fmaf(hk, wh.y, gf));
            gg = fmaf(xk, wi.z, fmaf(hk, wh.z, gg));
            go = fmaf(xk, wi.w, fmaf(hk, wh.w, go));
        }
        gi += __shfl_xor(gi, 32, 64);
        gf += __shfl_xor(gf, 32, 64);
        gg += __shfl_xor(gg, 32, 64);
        go += __shfl_xor(go, 32, 64);
        c = sigm(gf) * c + sigm(gi) * tanh_f(gg);
        h = sigm(go) * tanh_f(c);
    }
    float acc = 0.0f;
    #pragma unroll
    for (int kk = 0; kk < 16; kk++) {
        int k = (half << 4) + kk;
        float hk = __shfl(h, k, 32);
        acc = fmaf(hk, fcT[k * 32 + j], acc);
    }
    acc += __shfl_xor(acc, 32, 64);
    if (half == 0 && j < OUT_F) out[(size_t)node * OUT_F + j] = fc_b[j] + acc;
}

// ---------------------------------------------------------------------------
extern "C" void kernel_launch(void* const* d_in, const int* in_sizes, int n_in,
                              void* d_out, int out_size, void* d_ws, size_t ws_size,
                              hipStream_t stream) {
    (void)in_sizes; (void)n_in; (void)out_size; (void)ws_size;
    const float* X       = (const float*)d_in[0];
    const int*   ei      = (const int*)d_in[1];
    const float* gat_w   = (const float*)d_in[2];
    const float* att_src = (const float*)d_in[3];
    const float* att_dst = (const float*)d_in[4];
    const float* gat_b   = (const float*)d_in[5];
    const float* w_ih0   = (const float*)d_in[6];
    const float* w_hh0   = (const float*)d_in[7];
    const float* b_ih0   = (const float*)d_in[8];
    const float* b_hh0   = (const float*)d_in[9];
    const float* w_ih1   = (const float*)d_in[10];
    const float* w_hh1   = (const float*)d_in[11];
    const float* b_ih1   = (const float*)d_in[12];
    const float* b_hh1   = (const float*)d_in[13];
    const float* fc_w    = (const float*)d_in[14];
    const float* fc_b    = (const float*)d_in[15];
    float* out = (float*)d_out;

    char* ws = (char*)d_ws;
    size_t off = 0;
    auto alloc_f = [&](size_t n) { float* p = (float*)(ws + off); off += n * sizeof(float); return p; };
    auto alloc_i = [&](size_t n) { int* p = (int*)(ws + off); off += n * sizeof(int); return p; };

    float* gat_out = alloc_f((size_t)N_NODES * T_STEPS * HID);   // 1.15M
    float* hs0     = alloc_f((size_t)N_NODES * T_STEPS * HID);   // 1.15M
    float* proj    = alloc_f(32);
    int* deg       = alloc_i(N_NODES);
    int* row_start = alloc_i(N_NODES + 1);
    int* cursor    = alloc_i(N_NODES);
    int* csr_src   = alloc_i(E_TOT);

    // projection coefficients + CSR by destination
    k_prep<<<1, 32, 0, stream>>>(gat_w, att_src, att_dst, proj);
    k_zero<<<(N_NODES + 255) / 256, 256, 0, stream>>>(deg, N_NODES);
    k_deg<<<(E_TOT + 255) / 256, 256, 0, stream>>>(ei, deg);
    k_scan<<<1, 256, 0, stream>>>(deg, row_start, cursor);
    k_scatter<<<(E_TOT + 255) / 256, 256, 0, stream>>>(ei, cursor, csr_src);
    // fused GAT (lin + softmax + aggregation + head mean + bias)
    k_gat<<<T_STEPS * N_NODES, 256, 0, stream>>>(X, row_start, csr_src, proj,
                                                 gat_w, gat_b, gat_out);
    // 2-layer LSTM + FC
    k_lstm0<<<N_NODES / 4, 256, 0, stream>>>(gat_out, w_ih0, w_hh0, b_ih0, b_hh0, hs0);
    k_lstm1<<<N_NODES / 4, 256, 0, stream>>>(hs0, w_ih1, w_hh1, b_ih1, b_hh1,
                                             fc_w, fc_b, out);
}

// Round 6
// 167.836 us; speedup vs baseline: 2.2476x; 1.2591x over previous
//
#include <hip/hip_runtime.h>
#include <math.h>

#define N_NODES 3000
#define T_STEPS 12
#define F_INP 2
#define HEADS 8
#define HID 32
#define E_EDGES 32000
#define E_TOT (E_EDGES + N_NODES)   // 35000 with self-loops
#define NEG_SLOPE 0.2f
#define OUT_F 24                    // F_OUT * T_OUT
#define CHUNKS 8                    // 8 slots x 8 chunks = 64 edges in regs

__device__ __forceinline__ float sigm(float x) {
    return 1.0f / (1.0f + __expf(-x));
}
__device__ __forceinline__ float tanh_f(float x) {
    return 1.0f - 2.0f / (__expf(2.0f * x) + 1.0f);
}
// broadcast lane l's value to all 64 lanes via scalar pipe (v_readlane).
// CONVERGENT: must be called at full exec when reading lanes that a
// divergent branch would mask off (see round-4 post-mortem).
__device__ __forceinline__ float rdlane(float v, int l) {
    return __int_as_float(__builtin_amdgcn_readlane(__float_as_int(v), l));
}

// ---------------------------------------------------------------------------
// k_init: zero deg (blocks 0..11) + compute proj (block 12).
// proj[w*8+h]: w=0 <gw_f0,att_src>, 1 <gw_f1,att_src>, 2 <gw_f0,att_dst>, 3 <gw_f1,att_dst>
// ---------------------------------------------------------------------------
__global__ void k_init(int* __restrict__ deg,
                       const float* __restrict__ gat_w,
                       const float* __restrict__ att_src,
                       const float* __restrict__ att_dst,
                       float* __restrict__ proj) {
    if (blockIdx.x < 12) {
        int i = blockIdx.x * 256 + threadIdx.x;
        if (i < N_NODES) deg[i] = 0;
    } else {
        int tid = threadIdx.x;
        if (tid < 32) {
            int h = tid & 7, w = tid >> 3;
            const float* att = (w < 2) ? att_src : att_dst;
            int f = w & 1;
            float s = 0.0f;
            for (int c = 0; c < 32; c++)
                s += gat_w[((h * 32 + c) * 2) + f] * att[h * 32 + c];
            proj[w * 8 + h] = s;
        }
    }
}

__global__ void k_deg(const int* __restrict__ ei, int* __restrict__ deg) {
    int i = blockIdx.x * blockDim.x + threadIdx.x;
    if (i >= E_TOT) return;
    int d = (i < E_EDGES) ? ei[E_EDGES + i] : (i - E_EDGES);
    atomicAdd(&deg[d], 1);
}

__global__ __launch_bounds__(256) void k_scan(const int* __restrict__ deg,
                                              int* __restrict__ row_start,
                                              int* __restrict__ cursor) {
    __shared__ int part[256];
    int tid = threadIdx.x;
    const int CH = (N_NODES + 255) / 256;   // 12
    int base = tid * CH;
    int s = 0;
    for (int i = 0; i < CH; i++) {
        int idx = base + i;
        if (idx < N_NODES) s += deg[idx];
    }
    part[tid] = s;
    __syncthreads();
    if (tid == 0) {
        int run = 0;
        for (int i = 0; i < 256; i++) { int tmp = part[i]; part[i] = run; run += tmp; }
        row_start[N_NODES] = run;           // == E_TOT
    }
    __syncthreads();
    int off = part[tid];
    for (int i = 0; i < CH; i++) {
        int idx = base + i;
        if (idx < N_NODES) {
            row_start[idx] = off;
            cursor[idx] = off;
            off += deg[idx];
        }
    }
}

__global__ void k_scatter(const int* __restrict__ ei, int* __restrict__ cursor,
                          int* __restrict__ csr_src) {
    int i = blockIdx.x * blockDim.x + threadIdx.x;
    if (i >= E_TOT) return;
    int s, d;
    if (i < E_EDGES) { s = ei[i]; d = ei[E_EDGES + i]; }
    else             { s = i - E_EDGES; d = s; }
    int pos = atomicAdd(&cursor[d], 1);
    csr_src[pos] = s;
}

// ---------------------------------------------------------------------------
// k_gat: one wave64 per (t,n). lanes = 8 heads x 8 slots. Edge values in
// registers (static unroll), reductions via shfl_xor(1,2,4); head-sum
// broadcast via v_readlane AT FULL EXEC (hoisted before the store branch).
// gat_out layout: [n][t][c]
// ---------------------------------------------------------------------------
__global__ __launch_bounds__(256) void k_gat(const float* __restrict__ X,
                                             const int* __restrict__ row_start,
                                             const int* __restrict__ csr_src,
                                             const float* __restrict__ proj,
                                             const float* __restrict__ gat_w,
                                             const float* __restrict__ gat_b,
                                             float* __restrict__ gat_out) {
    int pair = blockIdx.x * 4 + (threadIdx.x >> 6);   // t*N + n
    int t = pair / N_NODES, n = pair - t * N_NODES;
    int lane = threadIdx.x & 63;
    int h = lane >> 3, slot = lane & 7;
    int rs = row_start[n];
    int deg = row_start[n + 1] - rs;     // >= 1 (self-loop)
    float ps0 = proj[h], ps1 = proj[8 + h];
    float pd0 = proj[16 + h], pd1 = proj[24 + h];
    float xd0 = X[(n * T_STEPS + t) * F_INP + 0];
    float xd1 = X[(n * T_STEPS + t) * F_INP + 1];
    float ad = fmaf(xd0, pd0, xd1 * pd1);

    float x0c[CHUNKS], x1c[CHUNKS], sc[CHUNKS];
    float m = -1e30f;
    #pragma unroll
    for (int c = 0; c < CHUNKS; c++) {
        if (8 * c < deg) {                       // wave-uniform branch
            int e = slot + 8 * c;
            int idx = rs + (e < deg ? e : deg - 1);
            int src = csr_src[idx];
            float2 xv = *(const float2*)&X[(src * T_STEPS + t) * F_INP];
            x0c[c] = xv.x; x1c[c] = xv.y;
            float s = fmaf(xv.x, ps0, fmaf(xv.y, ps1, ad));
            s = (s > 0.0f) ? s : NEG_SLOPE * s;
            sc[c] = (e < deg) ? s : -1e30f;
            m = fmaxf(m, sc[c]);
        } else { x0c[c] = 0.0f; x1c[c] = 0.0f; sc[c] = -1e30f; }
    }
    // deg > 64 fallback (never taken for this graph; wave-uniform)
    for (int e = 64 + slot; e < deg; e += 8) {
        int src = csr_src[rs + e];
        float2 xv = *(const float2*)&X[(src * T_STEPS + t) * F_INP];
        float s = fmaf(xv.x, ps0, fmaf(xv.y, ps1, ad));
        s = (s > 0.0f) ? s : NEG_SLOPE * s;
        m = fmaxf(m, s);
    }
    m = fmaxf(m, __shfl_xor(m, 1, 64));
    m = fmaxf(m, __shfl_xor(m, 2, 64));
    m = fmaxf(m, __shfl_xor(m, 4, 64));

    float den = 0.0f, S0 = 0.0f, S1 = 0.0f;
    #pragma unroll
    for (int c = 0; c < CHUNKS; c++) {
        if (8 * c < deg) {
            float a = __expf(sc[c] - m);          // masked slots: exp(-1e30)=0
            den += a;
            S0 = fmaf(a, x0c[c], S0);
            S1 = fmaf(a, x1c[c], S1);
        }
    }
    for (int e = 64 + slot; e < deg; e += 8) {    // fallback recompute
        int src = csr_src[rs + e];
        float2 xv = *(const float2*)&X[(src * T_STEPS + t) * F_INP];
        float s = fmaf(xv.x, ps0, fmaf(xv.y, ps1, ad));
        s = (s > 0.0f) ? s : NEG_SLOPE * s;
        float a = __expf(s - m);
        den += a; S0 = fmaf(a, xv.x, S0); S1 = fmaf(a, xv.y, S1);
    }
    #pragma unroll
    for (int mm = 1; mm <= 4; mm <<= 1) {
        den += __shfl_xor(den, mm, 64);
        S0  += __shfl_xor(S0,  mm, 64);
        S1  += __shfl_xor(S1,  mm, 64);
    }
    float inv = 0.125f / den;
    float v0 = S0 * inv, v1 = S1 * inv;

    // Broadcast per-head sums to ALL lanes at FULL EXEC (readlane is
    // convergent -> cannot be sunk into a divergent branch). This is the
    // round-4 bug fix: previously v0/v1 were consumed only under
    // if(lane<32), so their defining fmuls could be exec-masked and lanes
    // 32..63 (heads 4..7) held garbage when read by readlane.
    float a0[HEADS], a1[HEADS];
    #pragma unroll
    for (int hh = 0; hh < HEADS; hh++) {
        a0[hh] = rdlane(v0, hh * 8);
        a1[hh] = rdlane(v1, hh * 8);
    }

    // branch-free projection: all lanes compute, lanes 0..31 store
    int cc = lane & 31;
    float acc = gat_b[cc];
    #pragma unroll
    for (int hh = 0; hh < HEADS; hh++) {
        float2 g = *(const float2*)&gat_w[(hh * 32 + cc) * 2];
        acc = fmaf(a0[hh], g.x, fmaf(a1[hh], g.y, acc));
    }
    if (lane < 32)
        gat_out[((size_t)n * T_STEPS + t) * HID + cc] = acc;
}

// ---------------------------------------------------------------------------
// k_lstm: fused 2-layer LSTM + FC. One wave64 per node.
// Split-gate: half 0 owns gates (i,f), half 1 owns (g,o); each holds its
// 2x32 weight columns in VGPRs. h broadcast via v_readlane (scalar pipe),
// always at full exec. x-projections precomputed in a parallel prologue.
// Zero LDS.
// ---------------------------------------------------------------------------
__global__ __launch_bounds__(64) void k_lstm(const float* __restrict__ xs,  // [n][t][32]
                                             const float* __restrict__ w_ih0,
                                             const float* __restrict__ w_hh0,
                                             const float* __restrict__ b_ih0,
                                             const float* __restrict__ b_hh0,
                                             const float* __restrict__ w_ih1,
                                             const float* __restrict__ w_hh1,
                                             const float* __restrict__ b_ih1,
                                             const float* __restrict__ b_hh1,
                                             const float* __restrict__ fc_w,
                                             const float* __restrict__ fc_b,
                                             float* __restrict__ out) {     // [n][24]
    int n = blockIdx.x;
    int lane = threadIdx.x;
    int j = lane & 31, half = lane >> 5;
    int rowA = half * 64 + j;        // gate i (half0) / g (half1)
    int rowB = half * 64 + 32 + j;   // gate f (half0) / o (half1)

    float wA[32], wB[32];
    #pragma unroll
    for (int q = 0; q < 8; q++) {
        float4 va = *(const float4*)&w_ih0[rowA * 32 + 4 * q];
        float4 vb = *(const float4*)&w_ih0[rowB * 32 + 4 * q];
        wA[4*q] = va.x; wA[4*q+1] = va.y; wA[4*q+2] = va.z; wA[4*q+3] = va.w;
        wB[4*q] = vb.x; wB[4*q+1] = vb.y; wB[4*q+2] = vb.z; wB[4*q+3] = vb.w;
    }
    float bA = b_ih0[rowA] + b_hh0[rowA];
    float bB = b_ih0[rowB] + b_hh0[rowB];

    // x rows (both halves load same addresses -> merged)
    float xrow[T_STEPS];
    #pragma unroll
    for (int t = 0; t < T_STEPS; t++)
        xrow[t] = xs[((size_t)n * T_STEPS + t) * HID + j];

    // layer-0 input projections (parallel across t)
    float gxa[T_STEPS], gxb[T_STEPS];
    #pragma unroll
    for (int t = 0; t < T_STEPS; t++) {
        float a = bA, b = bB;
        #pragma unroll
        for (int k = 0; k < 32; k++) {
            float xk = rdlane(xrow[t], k);
            a = fmaf(xk, wA[k], a);
            b = fmaf(xk, wB[k], b);
        }
        gxa[t] = a; gxb[t] = b;
    }
    // swap in w_hh0
    #pragma unroll
    for (int q = 0; q < 8; q++) {
        float4 va = *(const float4*)&w_hh0[rowA * 32 + 4 * q];
        float4 vb = *(const float4*)&w_hh0[rowB * 32 + 4 * q];
        wA[4*q] = va.x; wA[4*q+1] = va.y; wA[4*q+2] = va.z; wA[4*q+3] = va.w;
        wB[4*q] = vb.x; wB[4*q+1] = vb.y; wB[4*q+2] = vb.z; wB[4*q+3] = vb.w;
    }
    // layer-0 recurrence
    float h = 0.0f, c = 0.0f;
    float h0s[T_STEPS];
    #pragma unroll
    for (int t = 0; t < T_STEPS; t++) {
        float gA = gxa[t], gB = gxb[t];
        #pragma unroll
        for (int k = 0; k < 32; k++) {
            float hk = rdlane(h, k);
            gA = fmaf(hk, wA[k], gA);
            gB = fmaf(hk, wB[k], gB);
        }
        float oA = __shfl_xor(gA, 32, 64);
        float oB = __shfl_xor(gB, 32, 64);
        float gi = half ? oA : gA;
        float gf = half ? oB : gB;
        float gg = half ? gA : oA;
        float go = half ? gB : oB;
        c = sigm(gf) * c + sigm(gi) * tanh_f(gg);
        h = sigm(go) * tanh_f(c);
        h0s[t] = h;
    }
    // layer-1 input projections from h0s
    float bA1 = b_ih1[rowA] + b_hh1[rowA];
    float bB1 = b_ih1[rowB] + b_hh1[rowB];
    #pragma unroll
    for (int q = 0; q < 8; q++) {
        float4 va = *(const float4*)&w_ih1[rowA * 32 + 4 * q];
        float4 vb = *(const float4*)&w_ih1[rowB * 32 + 4 * q];
        wA[4*q] = va.x; wA[4*q+1] = va.y; wA[4*q+2] = va.z; wA[4*q+3] = va.w;
        wB[4*q] = vb.x; wB[4*q+1] = vb.y; wB[4*q+2] = vb.z; wB[4*q+3] = vb.w;
    }
    #pragma unroll
    for (int t = 0; t < T_STEPS; t++) {
        float a = bA1, b = bB1;
        #pragma unroll
        for (int k = 0; k < 32; k++) {
            float xk = rdlane(h0s[t], k);
            a = fmaf(xk, wA[k], a);
            b = fmaf(xk, wB[k], b);
        }
        gxa[t] = a; gxb[t] = b;
    }
    #pragma unroll
    for (int q = 0; q < 8; q++) {
        float4 va = *(const float4*)&w_hh1[rowA * 32 + 4 * q];
        float4 vb = *(const float4*)&w_hh1[rowB * 32 + 4 * q];
        wA[4*q] = va.x; wA[4*q+1] = va.y; wA[4*q+2] = va.z; wA[4*q+3] = va.w;
        wB[4*q] = vb.x; wB[4*q+1] = vb.y; wB[4*q+2] = vb.z; wB[4*q+3] = vb.w;
    }
    // layer-1 recurrence
    h = 0.0f; c = 0.0f;
    #pragma unroll
    for (int t = 0; t < T_STEPS; t++) {
        float gA = gxa[t], gB = gxb[t];
        #pragma unroll
        for (int k = 0; k < 32; k++) {
            float hk = rdlane(h, k);
            gA = fmaf(hk, wA[k], gA);
            gB = fmaf(hk, wB[k], gB);
        }
        float oA = __shfl_xor(gA, 32, 64);
        float oB = __shfl_xor(gB, 32, 64);
        float gi = half ? oA : gA;
        float gf = half ? oB : gB;
        float gg = half ? gA : oA;
        float go = half ? gB : oB;
        c = sigm(gf) * c + sigm(gi) * tanh_f(gg);
        h = sigm(go) * tanh_f(c);
    }
    // FC head: all lanes compute (o clamped), lanes 0..23 store.
    int o = (lane < OUT_F) ? lane : (OUT_F - 1);
    float fw[32];
    #pragma unroll
    for (int q = 0; q < 8; q++) {
        float4 v = *(const float4*)&fc_w[o * 32 + 4 * q];
        fw[4*q] = v.x; fw[4*q+1] = v.y; fw[4*q+2] = v.z; fw[4*q+3] = v.w;
    }
    float acc = fc_b[o];
    #pragma unroll
    for (int k = 0; k < 32; k++) {
        float hk = rdlane(h, k);
        acc = fmaf(hk, fw[k], acc);
    }
    if (lane < OUT_F) out[(size_t)n * OUT_F + lane] = acc;
}

// ---------------------------------------------------------------------------
extern "C" void kernel_launch(void* const* d_in, const int* in_sizes, int n_in,
                              void* d_out, int out_size, void* d_ws, size_t ws_size,
                              hipStream_t stream) {
    (void)in_sizes; (void)n_in; (void)out_size; (void)ws_size;
    const float* X       = (const float*)d_in[0];
    const int*   ei      = (const int*)d_in[1];
    const float* gat_w   = (const float*)d_in[2];
    const float* att_src = (const float*)d_in[3];
    const float* att_dst = (const float*)d_in[4];
    const float* gat_b   = (const float*)d_in[5];
    const float* w_ih0   = (const float*)d_in[6];
    const float* w_hh0   = (const float*)d_in[7];
    const float* b_ih0   = (const float*)d_in[8];
    const float* b_hh0   = (const float*)d_in[9];
    const float* w_ih1   = (const float*)d_in[10];
    const float* w_hh1   = (const float*)d_in[11];
    const float* b_ih1   = (const float*)d_in[12];
    const float* b_hh1   = (const float*)d_in[13];
    const float* fc_w    = (const float*)d_in[14];
    const float* fc_b    = (const float*)d_in[15];
    float* out = (float*)d_out;

    char* ws = (char*)d_ws;
    size_t off = 0;
    auto alloc_f = [&](size_t n) { float* p = (float*)(ws + off); off += n * sizeof(float); return p; };
    auto alloc_i = [&](size_t n) { int* p = (int*)(ws + off); off += n * sizeof(int); return p; };

    float* gat_out = alloc_f((size_t)N_NODES * T_STEPS * HID);
    float* proj    = alloc_f(32);
    int* deg       = alloc_i(N_NODES);
    int* row_start = alloc_i(N_NODES + 1);
    int* cursor    = alloc_i(N_NODES);
    int* csr_src   = alloc_i(E_TOT);

    k_init<<<13, 256, 0, stream>>>(deg, gat_w, att_src, att_dst, proj);
    k_deg<<<(E_TOT + 255) / 256, 256, 0, stream>>>(ei, deg);
    k_scan<<<1, 256, 0, stream>>>(deg, row_start, cursor);
    k_scatter<<<(E_TOT + 255) / 256, 256, 0, stream>>>(ei, cursor, csr_src);
    k_gat<<<(T_STEPS * N_NODES) / 4, 256, 0, stream>>>(X, row_start, csr_src, proj,
                                                       gat_w, gat_b, gat_out);
    k_lstm<<<N_NODES, 64, 0, stream>>>(gat_out, w_ih0, w_hh0, b_ih0, b_hh0,
                                       w_ih1, w_hh1, b_ih1, b_hh1,
                                       fc_w, fc_b, out);
}